// Round 9
// baseline (181.695 us; speedup 1.0000x reference)
//
#include <hip/hip_runtime.h>
#include <cstdint>
#include <cstddef>

// Problem constants (fixed by reference)
#define SLEN 2048
#define BSZ  2
#define EDIM 1024
#define NHEAD 16
#define DHEAD 64
#define PFW  16
#define NTOK (SLEN*BSZ)   // 4096

#define BK 32

typedef __attribute__((ext_vector_type(8))) short short8;   // 8 x bf16 bits
typedef __attribute__((ext_vector_type(4))) float floatx4;
typedef __attribute__((ext_vector_type(4))) int   int4v;    // 16 B (i8 MFMA frag / i32 acc)

__device__ __forceinline__ short f2bf(float f) {
  union { float f; uint32_t u; } v; v.f = f;
  uint32_t r = v.u + 0x7fffu + ((v.u >> 16) & 1u);   // round-nearest-even
  return (short)(r >> 16);
}
__device__ __forceinline__ float bf2f(short s) {
  union { uint32_t u; float f; } v; v.u = ((uint32_t)(uint16_t)s) << 16;
  return v.f;
}
__device__ __forceinline__ int q8(float f, float inv) {
  int q = __float2int_rn(f * inv);
  return min(127, max(-127, q));
}

// async global->LDS, 16B per lane; LDS dest = wave-uniform base + lane*16
__device__ __forceinline__ void async16(const void* g, void* l) {
  __builtin_amdgcn_global_load_lds((const __attribute__((address_space(1))) void*)g,
                                   (__attribute__((address_space(3))) void*)l,
                                   16, 0, 0);
}

// ---------------------------------------------------------------------------
// prep: blocks [0,NTOK): LayerNorm rows -> int8 + per-row scale.
//       blocks [NTOK, NTOK+4096): weight transpose tiles -> Wt bf16.
// ---------------------------------------------------------------------------
__global__ __launch_bounds__(256) void prep_kernel(
    const float* __restrict__ x, const float* __restrict__ g,
    const float* __restrict__ b, char* __restrict__ xn_i8,
    float* __restrict__ xn_scl,
    const float* __restrict__ W0, const float* __restrict__ W1,
    const float* __restrict__ W2, const float* __restrict__ W3,
    short* __restrict__ Wt_base)
{
  const int bid = blockIdx.x;
  const int tid = threadIdx.x;

  if (bid < NTOK) {
    const int row = bid;
    const float4 v = ((const float4*)(x + (size_t)row * EDIM))[tid];
    float s  = v.x + v.y + v.z + v.w;
    float ss = v.x * v.x + v.y * v.y + v.z * v.z + v.w * v.w;
#pragma unroll
    for (int off = 32; off; off >>= 1) {
      s  += __shfl_xor(s, off);
      ss += __shfl_xor(ss, off);
    }
    __shared__ float ws_s[4], ws_ss[4], ws_m[4];
    const int lane = tid & 63, wave = tid >> 6;
    if (lane == 0) { ws_s[wave] = s; ws_ss[wave] = ss; }
    __syncthreads();
    s  = ws_s[0] + ws_s[1] + ws_s[2] + ws_s[3];
    ss = ws_ss[0] + ws_ss[1] + ws_ss[2] + ws_ss[3];

    const float mean = s * (1.0f / EDIM);
    const float var  = ss * (1.0f / EDIM) - mean * mean;
    const float rs   = rsqrtf(var + 1e-5f);

    const float4 gv = ((const float4*)g)[tid];
    const float4 bv = ((const float4*)b)[tid];
    const float n0 = (v.x - mean) * rs * gv.x + bv.x;
    const float n1 = (v.y - mean) * rs * gv.y + bv.y;
    const float n2 = (v.z - mean) * rs * gv.z + bv.z;
    const float n3 = (v.w - mean) * rs * gv.w + bv.w;

    float am = fmaxf(fmaxf(fabsf(n0), fabsf(n1)), fmaxf(fabsf(n2), fabsf(n3)));
#pragma unroll
    for (int off = 32; off; off >>= 1) am = fmaxf(am, __shfl_xor(am, off));
    if (lane == 0) ws_m[wave] = am;
    __syncthreads();
    am = fmaxf(fmaxf(ws_m[0], ws_m[1]), fmaxf(ws_m[2], ws_m[3]));

    const float inv = (am > 1e-30f) ? 127.0f / am : 0.0f;
    const int q0 = q8(n0, inv), q1 = q8(n1, inv), q2 = q8(n2, inv), q3 = q8(n3, inv);
    const uint32_t pack = (uint32_t)(q0 & 0xff) | ((uint32_t)(q1 & 0xff) << 8) |
                          ((uint32_t)(q2 & 0xff) << 16) | ((uint32_t)(q3 & 0xff) << 24);
    ((uint32_t*)(xn_i8 + (size_t)row * EDIM))[tid] = pack;
    if (tid == 0) xn_scl[row] = am * (1.0f / 127.0f);
  } else {
    const int t = bid - NTOK;
    const int z = t >> 10;
    const int rem = t & 1023;
    const int n0 = (rem & 31) * 32;
    const int k0 = (rem >> 5) * 32;
    const float* W = (z == 0) ? W0 : (z == 1) ? W1 : (z == 2) ? W2 : W3;
    short* Wt = Wt_base + (size_t)z * EDIM * EDIM;

    __shared__ float tile[32][33];
    const int tx = tid & 31;
    const int ty = tid >> 5;
#pragma unroll
    for (int i = 0; i < 4; ++i)
      tile[ty + i * 8][tx] = W[(size_t)(k0 + ty + i * 8) * EDIM + n0 + tx];
    __syncthreads();
#pragma unroll
    for (int i = 0; i < 4; ++i)
      Wt[(size_t)(n0 + ty + i * 8) * EDIM + k0 + tx] = f2bf(tile[tx][ty + i * 8]);
  }
}

// ---------------------------------------------------------------------------
// quant_w: one block per Wt row R (all 4 matrices): bf16 -> int8 + per-row
// (= per output column) scale.
// ---------------------------------------------------------------------------
__global__ __launch_bounds__(256) void quant_w(
    const short* __restrict__ Wt, char* __restrict__ w_i8,
    float* __restrict__ w_scl)
{
  const int R = blockIdx.x;      // 0..4095
  const int tid = threadIdx.x;
  const short4 s4 = ((const short4*)(Wt + (size_t)R * EDIM))[tid];
  const float w0 = bf2f(s4.x), w1 = bf2f(s4.y), w2 = bf2f(s4.z), w3 = bf2f(s4.w);

  float am = fmaxf(fmaxf(fabsf(w0), fabsf(w1)), fmaxf(fabsf(w2), fabsf(w3)));
#pragma unroll
  for (int off = 32; off; off >>= 1) am = fmaxf(am, __shfl_xor(am, off));
  __shared__ float wm[4];
  const int lane = tid & 63, wave = tid >> 6;
  if (lane == 0) wm[wave] = am;
  __syncthreads();
  am = fmaxf(fmaxf(wm[0], wm[1]), fmaxf(wm[2], wm[3]));

  const float inv = (am > 1e-30f) ? 127.0f / am : 0.0f;
  const int q0 = q8(w0, inv), q1 = q8(w1, inv), q2 = q8(w2, inv), q3 = q8(w3, inv);
  const uint32_t pack = (uint32_t)(q0 & 0xff) | ((uint32_t)(q1 & 0xff) << 8) |
                        ((uint32_t)(q2 & 0xff) << 16) | ((uint32_t)(q3 & 0xff) << 24);
  ((uint32_t*)(w_i8 + (size_t)R * EDIM))[tid] = pack;
  if (tid == 0) w_scl[R] = am * (1.0f / 127.0f);
}

// ---------------------------------------------------------------------------
// QKV projection, W8A8 int8, NO-LDS register-direct K-loop.
// Each lane's MFMA fragment is 16 contiguous bytes in global (row*1024 +
// quad*16), loaded as global_load_dwordx4. No __syncthreads in the loop --
// register double-buffer (load k+1 while computing k), compiler emits
// partial vmcnt waits. XCD swizzle keeps B-slab (0.4 MB) + A (4 MB) in L2.
// ---------------------------------------------------------------------------
__global__ __launch_bounds__(256) void gemm_qkv_i8(
    const char* __restrict__ xn_i8, const float* __restrict__ xn_scl,
    const char* __restrict__ w_i8, const float* __restrict__ w_scl,
    const float* __restrict__ bq, const float* __restrict__ bk,
    const float* __restrict__ bv, short* __restrict__ qkv_base)
{
  const int bid  = blockIdx.x;           // 0..767
  const int xcd  = bid & 7;
  const int slot = bid >> 3;             // 0..95
  const int nz   = xcd * 3 + slot / 32;  // 0..23
  const int mt   = slot & 31;            // 0..31
  const int z    = nz >> 3;              // 0..2
  const int nt   = nz & 7;               // 0..7

  const char*  Bt   = w_i8 + (size_t)z * EDIM * EDIM;
  const float* bscl = w_scl + z * EDIM;
  const float* bias = (z == 0) ? bq : (z == 1) ? bk : bv;
  short* out        = qkv_base + (size_t)z * NTOK * EDIM;

  const int bm = mt * 128;
  const int bn = nt * 128;
  const int tid  = threadIdx.x;
  const int lane = tid & 63;
  const int wave = tid >> 6;

  const int wm  = (wave >> 1) * 64;
  const int wn  = (wave & 1) * 64;
  const int l16 = lane & 15;
  const int kq  = (lane >> 4) * 16;     // fragment k-byte offset

  // per-lane fragment base pointers (advance by 64 B per k-iter)
  const char* ap[4];
  const char* bp[4];
#pragma unroll
  for (int mi = 0; mi < 4; ++mi)
    ap[mi] = xn_i8 + (size_t)(bm + wm + mi * 16 + l16) * EDIM + kq;
#pragma unroll
  for (int ni = 0; ni < 4; ++ni)
    bp[ni] = Bt + (size_t)(bn + wn + ni * 16 + l16) * EDIM + kq;

  int4v acc[4][4];
#pragma unroll
  for (int i = 0; i < 4; ++i)
#pragma unroll
    for (int j = 0; j < 4; ++j) { int4v zz = {0, 0, 0, 0}; acc[i][j] = zz; }

  int4v af[2][4], bf[2][4];
#pragma unroll
  for (int mi = 0; mi < 4; ++mi) af[0][mi] = *(const int4v*)ap[mi];
#pragma unroll
  for (int ni = 0; ni < 4; ++ni) bf[0][ni] = *(const int4v*)bp[ni];

#pragma unroll
  for (int ki = 0; ki < 16; ++ki) {
    const int cur = ki & 1;
    const int nxt = cur ^ 1;
    if (ki < 15) {
      const int koff = (ki + 1) * 64;
#pragma unroll
      for (int mi = 0; mi < 4; ++mi) af[nxt][mi] = *(const int4v*)(ap[mi] + koff);
#pragma unroll
      for (int ni = 0; ni < 4; ++ni) bf[nxt][ni] = *(const int4v*)(bp[ni] + koff);
    }
#pragma unroll
    for (int mi = 0; mi < 4; ++mi)
#pragma unroll
      for (int ni = 0; ni < 4; ++ni)
        acc[mi][ni] = __builtin_amdgcn_mfma_i32_16x16x64_i8(
            af[cur][mi], bf[cur][ni], acc[mi][ni], 0, 0, 0);
  }

  const int r0 = bm + wm + ((lane >> 4) * 4);
  const int c0 = bn + wn + l16;
#pragma unroll
  for (int mi = 0; mi < 4; ++mi) {
    float sa[4];
#pragma unroll
    for (int r = 0; r < 4; ++r) sa[r] = xn_scl[r0 + mi * 16 + r];
#pragma unroll
    for (int ni = 0; ni < 4; ++ni) {
      const int4v v = acc[mi][ni];
      const int col = c0 + ni * 16;
      const float sb = bscl[col];
      const float bb = bias[col];
#pragma unroll
      for (int r = 0; r < 4; ++r) {
        const int row = r0 + mi * 16 + r;
        out[(size_t)row * EDIM + col] = f2bf((float)v[r] * (sa[r] * sb) + bb);
      }
    }
  }
}

// ---------------------------------------------------------------------------
// O projection, W8A8 int8 with per-(row,head) A-scales (R7 version).
// ---------------------------------------------------------------------------
__global__ __launch_bounds__(256) void gemm_o_i8(
    const char* __restrict__ A8, const float* __restrict__ a_scl,
    const char* __restrict__ w_i8, const float* __restrict__ w_scl,
    const float* __restrict__ bo, const float* __restrict__ residual,
    float* __restrict__ out)
{
  __shared__ __align__(16) char As[64 * 64];     // 4 KB
  __shared__ __align__(16) char Bs[128 * 64];    // 8 KB
  __shared__ float sa_lds[64 * 17];              // per-(row,head) scales, padded

  const int bm = blockIdx.x * 64;
  const int bn = blockIdx.y * 128;
  const int tid  = threadIdx.x;
  const int lane = tid & 63;
  const int wave = tid >> 6;

#pragma unroll
  for (int i = 0; i < 4; ++i) {
    const int e = tid + i * 256;          // 0..1023
    const int row = e >> 4, h = e & 15;
    sa_lds[row * 17 + h] = a_scl[(size_t)(bm + row) * NHEAD + h];
  }

  floatx4 facc[2][4];
#pragma unroll
  for (int i = 0; i < 2; ++i)
#pragma unroll
    for (int j = 0; j < 4; ++j) { floatx4 zz = {0.f, 0.f, 0.f, 0.f}; facc[i][j] = zz; }

  const int lrow  = lane >> 2;
  const int lcolB = (lane & 3) * 16;
  const char* gA0 = A8 + (size_t)(bm + wave * 16 + lrow) * EDIM + lcolB;
  const char* gB0 = w_i8 + (size_t)3 * EDIM * EDIM +
                    (size_t)(bn + wave * 32 + lrow) * EDIM + lcolB;
  const char* gB1 = gB0 + (size_t)16 * EDIM;
  char* lA0 = As + wave * 1024;
  char* lB0 = Bs + wave * 2048;
  char* lB1 = lB0 + 1024;

  const int wm  = (wave >> 1) * 32;   // 0 or 32
  const int wn  = (wave & 1) * 64;    // 0 or 64
  const int fr  = lane & 15;
  const int fqB = (lane >> 4) * 16;
  const int q4  = lane >> 4;

  for (int ki = 0; ki < 16; ++ki) {
    async16(gA0, lA0);
    async16(gB0, lB0); async16(gB1, lB1);
    gA0 += 64; gB0 += 64; gB1 += 64;
    __syncthreads();

    int4v af[2], bf[4];
#pragma unroll
    for (int mi = 0; mi < 2; ++mi)
      af[mi] = *(const int4v*)(As + (size_t)(wm + mi * 16 + fr) * 64 + fqB);
#pragma unroll
    for (int ni = 0; ni < 4; ++ni)
      bf[ni] = *(const int4v*)(Bs + (size_t)(wn + ni * 16 + fr) * 64 + fqB);

    float sa_v[2][4];
#pragma unroll
    for (int mi = 0; mi < 2; ++mi)
#pragma unroll
      for (int r = 0; r < 4; ++r)
        sa_v[mi][r] = sa_lds[(wm + mi * 16 + q4 * 4 + r) * 17 + ki];

#pragma unroll
    for (int mi = 0; mi < 2; ++mi)
#pragma unroll
      for (int ni = 0; ni < 4; ++ni) {
        const int4v zz = {0, 0, 0, 0};
        const int4v t = __builtin_amdgcn_mfma_i32_16x16x64_i8(
            af[mi], bf[ni], zz, 0, 0, 0);
#pragma unroll
        for (int r = 0; r < 4; ++r)
          facc[mi][ni][r] += sa_v[mi][r] * (float)t[r];
      }
    __syncthreads();
  }

  const int r0 = bm + wm + q4 * 4;
  const int c0 = bn + wn + (lane & 15);
#pragma unroll
  for (int mi = 0; mi < 2; ++mi)
#pragma unroll
    for (int ni = 0; ni < 4; ++ni) {
      const int col = c0 + ni * 16;
      const float sb = w_scl[3 * EDIM + col];
      const float bb = bo[col];
#pragma unroll
      for (int r = 0; r < 4; ++r) {
        const int row = r0 + mi * 16 + r;
        const size_t idx = (size_t)row * EDIM + col;
        out[idx] = residual[idx] + facc[mi][ni][r] * sb + bb;
      }
    }
}

// ---------------------------------------------------------------------------
// MFMA attention; epilogue quantizes output to i8 with per-(row,head) scale.
// ---------------------------------------------------------------------------
#define VT_LD 80
#define PB_LD 40

__global__ __launch_bounds__(256) void attn_mfma(
    const short* __restrict__ Q, const short* __restrict__ K,
    const short* __restrict__ V, char* __restrict__ O8,
    float* __restrict__ a_scl)
{
  const int tid  = threadIdx.x;
  const int lane = tid & 63;
  const int wave = tid >> 6;
  const int quad = lane >> 4;
  const int l16  = lane & 15;

  const int bh = blockIdx.y;
  const int h  = bh & (NHEAD - 1);
  const int b  = bh >> 4;
  const int s_blk = blockIdx.x * 64;
  const int col0  = h * DHEAD;

  __shared__ __align__(16) short VT[64 * VT_LD];
  __shared__ __align__(16) short Pb[4][16 * PB_LD];

  for (int task = tid; task < 320; task += 256) {
    const int kp  = task >> 3;
    const int dg  = task & 7;
    const int kk0 = kp * 2;
    int sA = s_blk - 15 + kk0;
    int sB = sA + 1;
    if (sA < 0) sA += SLEN;  if (sA >= SLEN) sA -= SLEN;
    if (sB < 0) sB += SLEN;  if (sB >= SLEN) sB -= SLEN;
    const short8 vA = *(const short8*)(V + (size_t)(sA * BSZ + b) * EDIM + col0 + dg * 8);
    const short8 vB = *(const short8*)(V + (size_t)(sB * BSZ + b) * EDIM + col0 + dg * 8);
#pragma unroll
    for (int j = 0; j < 8; ++j) {
      const int d = dg * 8 + j;
      const uint32_t pack = (uint32_t)(uint16_t)vA[j] | ((uint32_t)(uint16_t)vB[j] << 16);
      *(uint32_t*)&VT[d * VT_LD + kk0] = pack;
    }
  }

  const int sw = s_blk + wave * 16;
  short8 aq[2];
  {
    const size_t base = (size_t)((sw + l16) * BSZ + b) * EDIM + col0 + quad * 8;
    aq[0] = *(const short8*)(Q + base);
    aq[1] = *(const short8*)(Q + base + 32);
  }
  short8 bkf[2][2];
#pragma unroll
  for (int T = 0; T < 2; ++T) {
    int ks = sw - 15 + T * 16 + l16;
    if (ks < 0) ks += SLEN;
    if (ks >= SLEN) ks -= SLEN;
    const size_t base = (size_t)(ks * BSZ + b) * EDIM + col0 + quad * 8;
    bkf[T][0] = *(const short8*)(K + base);
    bkf[T][1] = *(const short8*)(K + base + 32);
  }

  floatx4 S[2];
  { floatx4 zz = {0.f, 0.f, 0.f, 0.f}; S[0] = zz; S[1] = zz; }
#pragma unroll
  for (int T = 0; T < 2; ++T) {
    S[T] = __builtin_amdgcn_mfma_f32_16x16x32_bf16(aq[0], bkf[T][0], S[T], 0, 0, 0);
    S[T] = __builtin_amdgcn_mfma_f32_16x16x32_bf16(aq[1], bkf[T][1], S[T], 0, 0, 0);
  }

  float sc[2][4];
#pragma unroll
  for (int T = 0; T < 2; ++T)
#pragma unroll
    for (int r = 0; r < 4; ++r) {
      const int m = quad * 4 + r;
      const int c = T * 16 + l16;
      const int d = c - m;
      sc[T][r] = (d >= 0 && d <= 15) ? S[T][r] * 0.125f : -1e30f;
    }
  float mx[4], sm[4];
#pragma unroll
  for (int r = 0; r < 4; ++r) mx[r] = fmaxf(sc[0][r], sc[1][r]);
#pragma unroll
  for (int off = 1; off <= 8; off <<= 1)
#pragma unroll
    for (int r = 0; r < 4; ++r) mx[r] = fmaxf(mx[r], __shfl_xor(mx[r], off));
  float p[2][4];
#pragma unroll
  for (int r = 0; r < 4; ++r) {
    p[0][r] = __expf(sc[0][r] - mx[r]);
    p[1][r] = __expf(sc[1][r] - mx[r]);
    sm[r] = p[0][r] + p[1][r];
  }
#pragma unroll
  for (int off = 1; off <= 8; off <<= 1)
#pragma unroll
    for (int r = 0; r < 4; ++r) sm[r] += __shfl_xor(sm[r], off);

  __syncthreads();

  short* Pw = Pb[wave];
#pragma unroll
  for (int T = 0; T < 2; ++T)
#pragma unroll
    for (int r = 0; r < 4; ++r) {
      const int m = quad * 4 + r;
      const int c = T * 16 + l16;
      Pw[m * PB_LD + c] = f2bf(p[T][r]);
    }
  __syncthreads();
  const short8 ap = *(const short8*)(Pw + l16 * PB_LD + quad * 8);

  floatx4 Oacc[4];
  { floatx4 zz = {0.f, 0.f, 0.f, 0.f}; Oacc[0] = zz; Oacc[1] = zz; Oacc[2] = zz; Oacc[3] = zz; }
#pragma unroll
  for (int nt = 0; nt < 4; ++nt) {
    const short8 bv = *(const short8*)(VT + (nt * 16 + l16) * VT_LD + wave * 16 + quad * 8);
    Oacc[nt] = __builtin_amdgcn_mfma_f32_16x16x32_bf16(ap, bv, Oacc[nt], 0, 0, 0);
  }

  // ---- i8 quantization of output rows (per row, this head)
  float vv[4][4];   // [nt][r]
  float am[4] = {0.f, 0.f, 0.f, 0.f};
#pragma unroll
  for (int nt = 0; nt < 4; ++nt)
#pragma unroll
    for (int r = 0; r < 4; ++r) {
      const float v = Oacc[nt][r] / sm[r];
      vv[nt][r] = v;
      am[r] = fmaxf(am[r], fabsf(v));
    }
#pragma unroll
  for (int off = 1; off <= 8; off <<= 1)
#pragma unroll
    for (int r = 0; r < 4; ++r) am[r] = fmaxf(am[r], __shfl_xor(am[r], off));

  float inv[4];
#pragma unroll
  for (int r = 0; r < 4; ++r) inv[r] = (am[r] > 1e-30f) ? 127.0f / am[r] : 0.0f;

#pragma unroll
  for (int nt = 0; nt < 4; ++nt)
#pragma unroll
    for (int r = 0; r < 4; ++r) {
      const int m = quad * 4 + r;
      const int row = (sw + m) * BSZ + b;
      O8[(size_t)row * EDIM + col0 + nt * 16 + l16] = (char)q8(vv[nt][r], inv[r]);
    }
  if (l16 == 0) {
#pragma unroll
    for (int r = 0; r < 4; ++r) {
      const int m = quad * 4 + r;
      const int row = (sw + m) * BSZ + b;
      a_scl[(size_t)row * NHEAD + h] = am[r] * (1.0f / 127.0f);
    }
  }
}

// ---------------------------------------------------------------------------
extern "C" void kernel_launch(void* const* d_in, const int* in_sizes, int n_in,
                              void* d_out, int out_size, void* d_ws, size_t ws_size,
                              hipStream_t stream) {
  const float* x    = (const float*)d_in[0];
  const float* ln_g = (const float*)d_in[1];
  const float* ln_b = (const float*)d_in[2];
  const float* Wq   = (const float*)d_in[3];
  const float* bq   = (const float*)d_in[4];
  const float* Wk   = (const float*)d_in[5];
  const float* bk   = (const float*)d_in[6];
  const float* Wv   = (const float*)d_in[7];
  const float* bv   = (const float*)d_in[8];
  const float* Wo   = (const float*)d_in[9];
  const float* bo   = (const float*)d_in[10];
  float* out = (float*)d_out;

  char* ws = (char*)d_ws;
  char*  xn_i8   = ws;                                      // 4 MB
  short* Wt      = (short*)(ws + ((size_t)4  << 20));       // 8 MB: 4x Wt bf16
  char*  w_i8    = ws + ((size_t)12 << 20);                 // 4 MB: 4x Wt i8
  short* QKV     = (short*)(ws + ((size_t)16 << 20));       // 24 MB bf16
  char*  attn_i8 = ws + ((size_t)40 << 20);                 // 4 MB i8
  float* xn_scl  = (float*)(ws + ((size_t)44 << 20));       // 16 KB
  float* w_scl   = (float*)(ws + ((size_t)44 << 20) + (1 << 16)); // 16 KB
  float* a_scl   = (float*)(ws + ((size_t)44 << 20) + (2 << 16)); // 256 KB

  prep_kernel<<<NTOK + 4096, 256, 0, stream>>>(x, ln_g, ln_b, xn_i8, xn_scl,
                                               Wq, Wk, Wv, Wo, Wt);
  quant_w<<<4 * EDIM, 256, 0, stream>>>(Wt, w_i8, w_scl);
  gemm_qkv_i8<<<768, 256, 0, stream>>>(xn_i8, xn_scl, w_i8, w_scl,
                                       bq, bk, bv, QKV);
  attn_mfma<<<dim3(SLEN / 64, BSZ * NHEAD), 256, 0, stream>>>(
      QKV, QKV + (size_t)NTOK * EDIM, QKV + (size_t)2 * NTOK * EDIM,
      attn_i8, a_scl);
  gemm_o_i8<<<dim3(NTOK / 64, EDIM / 128), 256, 0, stream>>>(
      attn_i8, a_scl, w_i8, w_scl, bo, x, out);
}

// Round 10
// 163.633 us; speedup vs baseline: 1.1104x; 1.1104x over previous
//
#include <hip/hip_runtime.h>
#include <cstdint>
#include <cstddef>

// Problem constants (fixed by reference)
#define SLEN 2048
#define BSZ  2
#define EDIM 1024
#define NHEAD 16
#define DHEAD 64
#define PFW  16
#define NTOK (SLEN*BSZ)   // 4096

typedef __attribute__((ext_vector_type(8))) short short8;   // 8 x bf16 bits
typedef __attribute__((ext_vector_type(4))) float floatx4;
typedef __attribute__((ext_vector_type(4))) int   int4v;    // 16 B (i8 MFMA frag / i32 acc)

__device__ __forceinline__ short f2bf(float f) {
  union { float f; uint32_t u; } v; v.f = f;
  uint32_t r = v.u + 0x7fffu + ((v.u >> 16) & 1u);   // round-nearest-even
  return (short)(r >> 16);
}
__device__ __forceinline__ float bf2f(short s) {
  union { uint32_t u; float f; } v; v.u = ((uint32_t)(uint16_t)s) << 16;
  return v.f;
}
__device__ __forceinline__ int q8(float f, float inv) {
  int q = __float2int_rn(f * inv);
  return min(127, max(-127, q));
}

// async global->LDS, 16B per lane; LDS dest = wave-uniform base + lane*16
__device__ __forceinline__ void async16(const void* g, void* l) {
  __builtin_amdgcn_global_load_lds((const __attribute__((address_space(1))) void*)g,
                                   (__attribute__((address_space(3))) void*)l,
                                   16, 0, 0);
}

// ---------------------------------------------------------------------------
// prep: blocks [0,NTOK): LayerNorm rows -> int8 + per-row scale.
//       blocks [NTOK, NTOK+4096): weight transpose tiles -> Wt bf16.
// ---------------------------------------------------------------------------
__global__ __launch_bounds__(256) void prep_kernel(
    const float* __restrict__ x, const float* __restrict__ g,
    const float* __restrict__ b, char* __restrict__ xn_i8,
    float* __restrict__ xn_scl,
    const float* __restrict__ W0, const float* __restrict__ W1,
    const float* __restrict__ W2, const float* __restrict__ W3,
    short* __restrict__ Wt_base)
{
  const int bid = blockIdx.x;
  const int tid = threadIdx.x;

  if (bid < NTOK) {
    const int row = bid;
    const float4 v = ((const float4*)(x + (size_t)row * EDIM))[tid];
    float s  = v.x + v.y + v.z + v.w;
    float ss = v.x * v.x + v.y * v.y + v.z * v.z + v.w * v.w;
#pragma unroll
    for (int off = 32; off; off >>= 1) {
      s  += __shfl_xor(s, off);
      ss += __shfl_xor(ss, off);
    }
    __shared__ float ws_s[4], ws_ss[4], ws_m[4];
    const int lane = tid & 63, wave = tid >> 6;
    if (lane == 0) { ws_s[wave] = s; ws_ss[wave] = ss; }
    __syncthreads();
    s  = ws_s[0] + ws_s[1] + ws_s[2] + ws_s[3];
    ss = ws_ss[0] + ws_ss[1] + ws_ss[2] + ws_ss[3];

    const float mean = s * (1.0f / EDIM);
    const float var  = ss * (1.0f / EDIM) - mean * mean;
    const float rs   = rsqrtf(var + 1e-5f);

    const float4 gv = ((const float4*)g)[tid];
    const float4 bv = ((const float4*)b)[tid];
    const float n0 = (v.x - mean) * rs * gv.x + bv.x;
    const float n1 = (v.y - mean) * rs * gv.y + bv.y;
    const float n2 = (v.z - mean) * rs * gv.z + bv.z;
    const float n3 = (v.w - mean) * rs * gv.w + bv.w;

    float am = fmaxf(fmaxf(fabsf(n0), fabsf(n1)), fmaxf(fabsf(n2), fabsf(n3)));
#pragma unroll
    for (int off = 32; off; off >>= 1) am = fmaxf(am, __shfl_xor(am, off));
    if (lane == 0) ws_m[wave] = am;
    __syncthreads();
    am = fmaxf(fmaxf(ws_m[0], ws_m[1]), fmaxf(ws_m[2], ws_m[3]));

    const float inv = (am > 1e-30f) ? 127.0f / am : 0.0f;
    const int q0 = q8(n0, inv), q1 = q8(n1, inv), q2 = q8(n2, inv), q3 = q8(n3, inv);
    const uint32_t pack = (uint32_t)(q0 & 0xff) | ((uint32_t)(q1 & 0xff) << 8) |
                          ((uint32_t)(q2 & 0xff) << 16) | ((uint32_t)(q3 & 0xff) << 24);
    ((uint32_t*)(xn_i8 + (size_t)row * EDIM))[tid] = pack;
    if (tid == 0) xn_scl[row] = am * (1.0f / 127.0f);
  } else {
    const int t = bid - NTOK;
    const int z = t >> 10;
    const int rem = t & 1023;
    const int n0 = (rem & 31) * 32;
    const int k0 = (rem >> 5) * 32;
    const float* W = (z == 0) ? W0 : (z == 1) ? W1 : (z == 2) ? W2 : W3;
    short* Wt = Wt_base + (size_t)z * EDIM * EDIM;

    __shared__ float tile[32][33];
    const int tx = tid & 31;
    const int ty = tid >> 5;
#pragma unroll
    for (int i = 0; i < 4; ++i)
      tile[ty + i * 8][tx] = W[(size_t)(k0 + ty + i * 8) * EDIM + n0 + tx];
    __syncthreads();
#pragma unroll
    for (int i = 0; i < 4; ++i)
      Wt[(size_t)(n0 + ty + i * 8) * EDIM + k0 + tx] = f2bf(tile[tx][ty + i * 8]);
  }
}

// ---------------------------------------------------------------------------
// quant_w: one block per Wt row R (all 4 matrices): bf16 -> int8 + per-row
// (= per output column) scale.
// ---------------------------------------------------------------------------
__global__ __launch_bounds__(256) void quant_w(
    const short* __restrict__ Wt, char* __restrict__ w_i8,
    float* __restrict__ w_scl)
{
  const int R = blockIdx.x;      // 0..4095
  const int tid = threadIdx.x;
  const short4 s4 = ((const short4*)(Wt + (size_t)R * EDIM))[tid];
  const float w0 = bf2f(s4.x), w1 = bf2f(s4.y), w2 = bf2f(s4.z), w3 = bf2f(s4.w);

  float am = fmaxf(fmaxf(fabsf(w0), fabsf(w1)), fmaxf(fabsf(w2), fabsf(w3)));
#pragma unroll
  for (int off = 32; off; off >>= 1) am = fmaxf(am, __shfl_xor(am, off));
  __shared__ float wm[4];
  const int lane = tid & 63, wave = tid >> 6;
  if (lane == 0) wm[wave] = am;
  __syncthreads();
  am = fmaxf(fmaxf(wm[0], wm[1]), fmaxf(wm[2], wm[3]));

  const float inv = (am > 1e-30f) ? 127.0f / am : 0.0f;
  const int q0 = q8(w0, inv), q1 = q8(w1, inv), q2 = q8(w2, inv), q3 = q8(w3, inv);
  const uint32_t pack = (uint32_t)(q0 & 0xff) | ((uint32_t)(q1 & 0xff) << 8) |
                        ((uint32_t)(q2 & 0xff) << 16) | ((uint32_t)(q3 & 0xff) << 24);
  ((uint32_t*)(w_i8 + (size_t)R * EDIM))[tid] = pack;
  if (tid == 0) w_scl[R] = am * (1.0f / 127.0f);
}

// ---------------------------------------------------------------------------
// QKV projection, W8A8 int8 (R6/R7-proven LDS K-loop): 128x128 tile,
// K-tile = 64 i8, 16 k-iters. Epilogue: z in {0,1} (Q,K) quantizes output
// to int8 with per-(row,head) scale (a wave's 64 cols = exactly one head);
// z==2 (V) writes bf16 as before.
// ---------------------------------------------------------------------------
__global__ __launch_bounds__(256) void gemm_qkv_i8(
    const char* __restrict__ xn_i8, const float* __restrict__ xn_scl,
    const char* __restrict__ w_i8, const float* __restrict__ w_scl,
    const float* __restrict__ bq, const float* __restrict__ bk,
    const float* __restrict__ bv,
    char* __restrict__ outQ, float* __restrict__ q_scl,
    char* __restrict__ outK, float* __restrict__ k_scl,
    short* __restrict__ outV)
{
  __shared__ __align__(16) char As[128 * 64];   // 8 KB
  __shared__ __align__(16) char Bs[128 * 64];   // 8 KB

  const int bid  = blockIdx.x;           // 0..767
  const int xcd  = bid & 7;
  const int slot = bid >> 3;             // 0..95
  const int nz   = xcd * 3 + slot / 32;  // 0..23
  const int mt   = slot & 31;            // 0..31
  const int z    = nz >> 3;              // 0..2
  const int nt   = nz & 7;               // 0..7

  const char*  Bt   = w_i8 + (size_t)z * EDIM * EDIM;
  const float* bscl = w_scl + z * EDIM;
  const float* bias = (z == 0) ? bq : (z == 1) ? bk : bv;

  const int bm = mt * 128;
  const int bn = nt * 128;
  const int tid  = threadIdx.x;
  const int lane = tid & 63;
  const int wave = tid >> 6;

  int4v acc[4][4];
#pragma unroll
  for (int i = 0; i < 4; ++i)
#pragma unroll
    for (int j = 0; j < 4; ++j) { int4v zz = {0, 0, 0, 0}; acc[i][j] = zz; }

  const int lrow  = lane >> 2;          // 0..15
  const int lcolB = (lane & 3) * 16;    // byte col 0,16,32,48
  const char* gA0 = xn_i8 + (size_t)(bm + wave * 32 + lrow) * EDIM + lcolB;
  const char* gA1 = gA0 + (size_t)16 * EDIM;
  const char* gB0 = Bt + (size_t)(bn + wave * 32 + lrow) * EDIM + lcolB;
  const char* gB1 = gB0 + (size_t)16 * EDIM;
  char* lA0 = As + wave * 2048;
  char* lA1 = lA0 + 1024;
  char* lB0 = Bs + wave * 2048;
  char* lB1 = lB0 + 1024;

  const int wm  = (wave >> 1) * 64;
  const int wn  = (wave & 1) * 64;
  const int fr  = lane & 15;
  const int fqB = (lane >> 4) * 16;     // byte offset within 64-B row

  for (int k0 = 0; k0 < EDIM; k0 += 64) {
    async16(gA0, lA0); async16(gA1, lA1);
    async16(gB0, lB0); async16(gB1, lB1);
    gA0 += 64; gA1 += 64; gB0 += 64; gB1 += 64;
    __syncthreads();

    int4v af[4], bf[4];
#pragma unroll
    for (int mi = 0; mi < 4; ++mi)
      af[mi] = *(const int4v*)(As + (size_t)(wm + mi * 16 + fr) * 64 + fqB);
#pragma unroll
    for (int ni = 0; ni < 4; ++ni)
      bf[ni] = *(const int4v*)(Bs + (size_t)(wn + ni * 16 + fr) * 64 + fqB);
#pragma unroll
    for (int mi = 0; mi < 4; ++mi)
#pragma unroll
      for (int ni = 0; ni < 4; ++ni)
        acc[mi][ni] = __builtin_amdgcn_mfma_i32_16x16x64_i8(
            af[mi], bf[ni], acc[mi][ni], 0, 0, 0);
    __syncthreads();
  }

  const int r0 = bm + wm + ((lane >> 4) * 4);
  const int c0 = bn + wn + fr;

  if (z == 2) {
    // ---- V: bf16 out (R6/R7 epilogue)
#pragma unroll
    for (int mi = 0; mi < 4; ++mi) {
      float sa[4];
#pragma unroll
      for (int r = 0; r < 4; ++r) sa[r] = xn_scl[r0 + mi * 16 + r];
#pragma unroll
      for (int ni = 0; ni < 4; ++ni) {
        const int4v v = acc[mi][ni];
        const int col = c0 + ni * 16;
        const float sb = bscl[col];
        const float bb = bias[col];
#pragma unroll
        for (int r = 0; r < 4; ++r) {
          const int row = r0 + mi * 16 + r;
          outV[(size_t)row * EDIM + col] = f2bf((float)v[r] * (sa[r] * sb) + bb);
        }
      }
    }
  } else {
    // ---- Q/K: int8 out with per-(row,head) scale. This wave's 64 cols =
    // head hW. Per-mi processing keeps VGPR pressure low.
    char*  out8 = (z == 0) ? outQ : outK;
    float* oscl = (z == 0) ? q_scl : k_scl;
    const int hW = (bn + wn) >> 6;     // 0..15
#pragma unroll
    for (int mi = 0; mi < 4; ++mi) {
      float sa[4];
#pragma unroll
      for (int r = 0; r < 4; ++r) sa[r] = xn_scl[r0 + mi * 16 + r];
      float vals[4][4];   // [ni][r]
      float am[4] = {0.f, 0.f, 0.f, 0.f};
#pragma unroll
      for (int ni = 0; ni < 4; ++ni) {
        const int4v v = acc[mi][ni];
        const int col = c0 + ni * 16;
        const float sb = bscl[col];
        const float bb = bias[col];
#pragma unroll
        for (int r = 0; r < 4; ++r) {
          const float f = (float)v[r] * (sa[r] * sb) + bb;
          vals[ni][r] = f;
          am[r] = fmaxf(am[r], fabsf(f));
        }
      }
      // absmax over the head's 64 cols: 4 ni (done) x 16 lanes (shfl in-quad)
#pragma unroll
      for (int off = 1; off <= 8; off <<= 1)
#pragma unroll
        for (int r = 0; r < 4; ++r) am[r] = fmaxf(am[r], __shfl_xor(am[r], off));
      float inv[4];
#pragma unroll
      for (int r = 0; r < 4; ++r) inv[r] = (am[r] > 1e-30f) ? 127.0f / am[r] : 0.0f;
#pragma unroll
      for (int ni = 0; ni < 4; ++ni) {
        const int col = c0 + ni * 16;
#pragma unroll
        for (int r = 0; r < 4; ++r) {
          const int row = r0 + mi * 16 + r;
          out8[(size_t)row * EDIM + col] = (char)q8(vals[ni][r], inv[r]);
        }
      }
      if (fr == 0) {
#pragma unroll
        for (int r = 0; r < 4; ++r)
          oscl[(size_t)(r0 + mi * 16 + r) * NHEAD + hW] = am[r] * (1.0f / 127.0f);
      }
    }
  }
}

// ---------------------------------------------------------------------------
// O projection, W8A8 int8 with per-(row,head) A-scales (R7-proven).
// ---------------------------------------------------------------------------
__global__ __launch_bounds__(256) void gemm_o_i8(
    const char* __restrict__ A8, const float* __restrict__ a_scl,
    const char* __restrict__ w_i8, const float* __restrict__ w_scl,
    const float* __restrict__ bo, const float* __restrict__ residual,
    float* __restrict__ out)
{
  __shared__ __align__(16) char As[64 * 64];     // 4 KB
  __shared__ __align__(16) char Bs[128 * 64];    // 8 KB
  __shared__ float sa_lds[64 * 17];              // per-(row,head) scales, padded

  const int bm = blockIdx.x * 64;
  const int bn = blockIdx.y * 128;
  const int tid  = threadIdx.x;
  const int lane = tid & 63;
  const int wave = tid >> 6;

#pragma unroll
  for (int i = 0; i < 4; ++i) {
    const int e = tid + i * 256;          // 0..1023
    const int row = e >> 4, h = e & 15;
    sa_lds[row * 17 + h] = a_scl[(size_t)(bm + row) * NHEAD + h];
  }

  floatx4 facc[2][4];
#pragma unroll
  for (int i = 0; i < 2; ++i)
#pragma unroll
    for (int j = 0; j < 4; ++j) { floatx4 zz = {0.f, 0.f, 0.f, 0.f}; facc[i][j] = zz; }

  const int lrow  = lane >> 2;
  const int lcolB = (lane & 3) * 16;
  const char* gA0 = A8 + (size_t)(bm + wave * 16 + lrow) * EDIM + lcolB;
  const char* gB0 = w_i8 + (size_t)3 * EDIM * EDIM +
                    (size_t)(bn + wave * 32 + lrow) * EDIM + lcolB;
  const char* gB1 = gB0 + (size_t)16 * EDIM;
  char* lA0 = As + wave * 1024;
  char* lB0 = Bs + wave * 2048;
  char* lB1 = lB0 + 1024;

  const int wm  = (wave >> 1) * 32;   // 0 or 32
  const int wn  = (wave & 1) * 64;    // 0 or 64
  const int fr  = lane & 15;
  const int fqB = (lane >> 4) * 16;
  const int q4  = lane >> 4;

  for (int ki = 0; ki < 16; ++ki) {
    async16(gA0, lA0);
    async16(gB0, lB0); async16(gB1, lB1);
    gA0 += 64; gB0 += 64; gB1 += 64;
    __syncthreads();

    int4v af[2], bf[4];
#pragma unroll
    for (int mi = 0; mi < 2; ++mi)
      af[mi] = *(const int4v*)(As + (size_t)(wm + mi * 16 + fr) * 64 + fqB);
#pragma unroll
    for (int ni = 0; ni < 4; ++ni)
      bf[ni] = *(const int4v*)(Bs + (size_t)(wn + ni * 16 + fr) * 64 + fqB);

    float sa_v[2][4];
#pragma unroll
    for (int mi = 0; mi < 2; ++mi)
#pragma unroll
      for (int r = 0; r < 4; ++r)
        sa_v[mi][r] = sa_lds[(wm + mi * 16 + q4 * 4 + r) * 17 + ki];

#pragma unroll
    for (int mi = 0; mi < 2; ++mi)
#pragma unroll
      for (int ni = 0; ni < 4; ++ni) {
        const int4v zz = {0, 0, 0, 0};
        const int4v t = __builtin_amdgcn_mfma_i32_16x16x64_i8(
            af[mi], bf[ni], zz, 0, 0, 0);
#pragma unroll
        for (int r = 0; r < 4; ++r)
          facc[mi][ni][r] += sa_v[mi][r] * (float)t[r];
      }
    __syncthreads();
  }

  const int r0 = bm + wm + q4 * 4;
  const int c0 = bn + wn + (lane & 15);
#pragma unroll
  for (int mi = 0; mi < 2; ++mi)
#pragma unroll
    for (int ni = 0; ni < 4; ++ni) {
      const int col = c0 + ni * 16;
      const float sb = w_scl[3 * EDIM + col];
      const float bb = bo[col];
#pragma unroll
      for (int r = 0; r < 4; ++r) {
        const int row = r0 + mi * 16 + r;
        const size_t idx = (size_t)row * EDIM + col;
        out[idx] = residual[idx] + facc[mi][ni][r] * sb + bb;
      }
    }
}

// ---------------------------------------------------------------------------
// MFMA attention, Q/K int8 (QK^T = one mfma_i32_16x16x64_i8 per key tile;
// K=64 = DHEAD so each lane's fragment is 16 contiguous global bytes).
// V bf16 PV path and i8 output epilogue unchanged (R7-proven).
// ---------------------------------------------------------------------------
#define VT_LD 80
#define PB_LD 40

__global__ __launch_bounds__(256) void attn_mfma(
    const char* __restrict__ Q8, const float* __restrict__ q_scl,
    const char* __restrict__ K8, const float* __restrict__ k_scl,
    const short* __restrict__ V, char* __restrict__ O8,
    float* __restrict__ a_scl)
{
  const int tid  = threadIdx.x;
  const int lane = tid & 63;
  const int wave = tid >> 6;
  const int quad = lane >> 4;
  const int l16  = lane & 15;

  const int bh = blockIdx.y;
  const int h  = bh & (NHEAD - 1);
  const int b  = bh >> 4;
  const int s_blk = blockIdx.x * 64;
  const int col0  = h * DHEAD;

  __shared__ __align__(16) short VT[64 * VT_LD];
  __shared__ __align__(16) short Pb[4][16 * PB_LD];

  for (int task = tid; task < 320; task += 256) {
    const int kp  = task >> 3;
    const int dg  = task & 7;
    const int kk0 = kp * 2;
    int sA = s_blk - 15 + kk0;
    int sB = sA + 1;
    if (sA < 0) sA += SLEN;  if (sA >= SLEN) sA -= SLEN;
    if (sB < 0) sB += SLEN;  if (sB >= SLEN) sB -= SLEN;
    const short8 vA = *(const short8*)(V + (size_t)(sA * BSZ + b) * EDIM + col0 + dg * 8);
    const short8 vB = *(const short8*)(V + (size_t)(sB * BSZ + b) * EDIM + col0 + dg * 8);
#pragma unroll
    for (int j = 0; j < 8; ++j) {
      const int d = dg * 8 + j;
      const uint32_t pack = (uint32_t)(uint16_t)vA[j] | ((uint32_t)(uint16_t)vB[j] << 16);
      *(uint32_t*)&VT[d * VT_LD + kk0] = pack;
    }
  }

  const int sw = s_blk + wave * 16;

  // ---- Q i8 A-fragment: 16 contiguous bytes (all 64 dims of this head)
  const int4v aq8 = *(const int4v*)(
      Q8 + (size_t)((sw + l16) * BSZ + b) * EDIM + col0 + quad * 16);
  // per-row Q scales (rows quad*4+r)
  float qs[4];
#pragma unroll
  for (int r = 0; r < 4; ++r)
    qs[r] = q_scl[(size_t)((sw + quad * 4 + r) * BSZ + b) * NHEAD + h];

  // ---- K i8 B-fragments + per-key scales: tiles T=0 (sw-15..sw), T=1 (+16)
  int4v bk8[2];
  float kscl[2];
#pragma unroll
  for (int T = 0; T < 2; ++T) {
    int ks = sw - 15 + T * 16 + l16;
    if (ks < 0) ks += SLEN;
    if (ks >= SLEN) ks -= SLEN;
    const size_t tok = (size_t)(ks * BSZ + b);
    bk8[T] = *(const int4v*)(K8 + tok * EDIM + col0 + quad * 16);
    kscl[T] = k_scl[tok * NHEAD + h];
  }

  // ---- scores: one i8 MFMA per tile (K=64 covers the whole head dim)
  int4v Si[2];
  { int4v zz = {0, 0, 0, 0}; Si[0] = zz; Si[1] = zz; }
#pragma unroll
  for (int T = 0; T < 2; ++T)
    Si[T] = __builtin_amdgcn_mfma_i32_16x16x64_i8(aq8, bk8[T], Si[T], 0, 0, 0);

  // ---- dequant + band mask + softmax
  float sc[2][4];
#pragma unroll
  for (int T = 0; T < 2; ++T)
#pragma unroll
    for (int r = 0; r < 4; ++r) {
      const int m = quad * 4 + r;
      const int c = T * 16 + l16;
      const int d = c - m;
      sc[T][r] = (d >= 0 && d <= 15)
                   ? (float)Si[T][r] * (qs[r] * kscl[T] * 0.125f)
                   : -1e30f;
    }
  float mx[4], sm[4];
#pragma unroll
  for (int r = 0; r < 4; ++r) mx[r] = fmaxf(sc[0][r], sc[1][r]);
#pragma unroll
  for (int off = 1; off <= 8; off <<= 1)
#pragma unroll
    for (int r = 0; r < 4; ++r) mx[r] = fmaxf(mx[r], __shfl_xor(mx[r], off));
  float p[2][4];
#pragma unroll
  for (int r = 0; r < 4; ++r) {
    p[0][r] = __expf(sc[0][r] - mx[r]);
    p[1][r] = __expf(sc[1][r] - mx[r]);
    sm[r] = p[0][r] + p[1][r];
  }
#pragma unroll
  for (int off = 1; off <= 8; off <<= 1)
#pragma unroll
    for (int r = 0; r < 4; ++r) sm[r] += __shfl_xor(sm[r], off);

  __syncthreads();

  short* Pw = Pb[wave];
#pragma unroll
  for (int T = 0; T < 2; ++T)
#pragma unroll
    for (int r = 0; r < 4; ++r) {
      const int m = quad * 4 + r;
      const int c = T * 16 + l16;
      Pw[m * PB_LD + c] = f2bf(p[T][r]);
    }
  __syncthreads();
  const short8 ap = *(const short8*)(Pw + l16 * PB_LD + quad * 8);

  floatx4 Oacc[4];
  { floatx4 zz = {0.f, 0.f, 0.f, 0.f}; Oacc[0] = zz; Oacc[1] = zz; Oacc[2] = zz; Oacc[3] = zz; }
#pragma unroll
  for (int nt = 0; nt < 4; ++nt) {
    const short8 bv = *(const short8*)(VT + (nt * 16 + l16) * VT_LD + wave * 16 + quad * 8);
    Oacc[nt] = __builtin_amdgcn_mfma_f32_16x16x32_bf16(ap, bv, Oacc[nt], 0, 0, 0);
  }

  // ---- i8 quantization of output rows (per row, this head)
  float vv[4][4];   // [nt][r]
  float am[4] = {0.f, 0.f, 0.f, 0.f};
#pragma unroll
  for (int nt = 0; nt < 4; ++nt)
#pragma unroll
    for (int r = 0; r < 4; ++r) {
      const float v = Oacc[nt][r] / sm[r];
      vv[nt][r] = v;
      am[r] = fmaxf(am[r], fabsf(v));
    }
#pragma unroll
  for (int off = 1; off <= 8; off <<= 1)
#pragma unroll
    for (int r = 0; r < 4; ++r) am[r] = fmaxf(am[r], __shfl_xor(am[r], off));

  float inv[4];
#pragma unroll
  for (int r = 0; r < 4; ++r) inv[r] = (am[r] > 1e-30f) ? 127.0f / am[r] : 0.0f;

#pragma unroll
  for (int nt = 0; nt < 4; ++nt)
#pragma unroll
    for (int r = 0; r < 4; ++r) {
      const int m = quad * 4 + r;
      const int row = (sw + m) * BSZ + b;
      O8[(size_t)row * EDIM + col0 + nt * 16 + l16] = (char)q8(vv[nt][r], inv[r]);
    }
  if (l16 == 0) {
#pragma unroll
    for (int r = 0; r < 4; ++r) {
      const int m = quad * 4 + r;
      const int row = (sw + m) * BSZ + b;
      a_scl[(size_t)row * NHEAD + h] = am[r] * (1.0f / 127.0f);
    }
  }
}

// ---------------------------------------------------------------------------
extern "C" void kernel_launch(void* const* d_in, const int* in_sizes, int n_in,
                              void* d_out, int out_size, void* d_ws, size_t ws_size,
                              hipStream_t stream) {
  const float* x    = (const float*)d_in[0];
  const float* ln_g = (const float*)d_in[1];
  const float* ln_b = (const float*)d_in[2];
  const float* Wq   = (const float*)d_in[3];
  const float* bq   = (const float*)d_in[4];
  const float* Wk   = (const float*)d_in[5];
  const float* bk   = (const float*)d_in[6];
  const float* Wv   = (const float*)d_in[7];
  const float* bv   = (const float*)d_in[8];
  const float* Wo   = (const float*)d_in[9];
  const float* bo   = (const float*)d_in[10];
  float* out = (float*)d_out;

  char* ws = (char*)d_ws;
  char*  xn_i8   = ws;                                      // 4 MB
  short* Wt      = (short*)(ws + ((size_t)4  << 20));       // 8 MB: 4x Wt bf16
  char*  w_i8    = ws + ((size_t)12 << 20);                 // 4 MB: 4x Wt i8
  char*  Q8      = ws + ((size_t)16 << 20);                 // 4 MB i8
  char*  K8      = ws + ((size_t)20 << 20);                 // 4 MB i8
  short* V16     = (short*)(ws + ((size_t)24 << 20));       // 8 MB bf16
  char*  attn_i8 = ws + ((size_t)32 << 20);                 // 4 MB i8
  float* xn_scl  = (float*)(ws + ((size_t)48 << 20));       // 16 KB
  float* w_scl   = (float*)(ws + ((size_t)48 << 20) + (1 << 18)); // 16 KB
  float* a_scl   = (float*)(ws + ((size_t)49 << 20));       // 256 KB
  float* q_scl   = (float*)(ws + ((size_t)50 << 20));       // 256 KB
  float* k_scl   = (float*)(ws + ((size_t)51 << 20));       // 256 KB

  prep_kernel<<<NTOK + 4096, 256, 0, stream>>>(x, ln_g, ln_b, xn_i8, xn_scl,
                                               Wq, Wk, Wv, Wo, Wt);
  quant_w<<<4 * EDIM, 256, 0, stream>>>(Wt, w_i8, w_scl);
  gemm_qkv_i8<<<768, 256, 0, stream>>>(xn_i8, xn_scl, w_i8, w_scl,
                                       bq, bk, bv,
                                       Q8, q_scl, K8, k_scl, V16);
  attn_mfma<<<dim3(SLEN / 64, BSZ * NHEAD), 256, 0, stream>>>(
      Q8, q_scl, K8, k_scl, V16, attn_i8, a_scl);
  gemm_o_i8<<<dim3(NTOK / 64, EDIM / 128), 256, 0, stream>>>(
      attn_i8, a_scl, w_i8, w_scl, bo, x, out);
}

// Round 11
// 152.153 us; speedup vs baseline: 1.1942x; 1.0755x over previous
//
#include <hip/hip_runtime.h>
#include <cstdint>
#include <cstddef>

// Problem constants (fixed by reference)
#define SLEN 2048
#define BSZ  2
#define EDIM 1024
#define NHEAD 16
#define DHEAD 64
#define PFW  16
#define NTOK (SLEN*BSZ)   // 4096

typedef __attribute__((ext_vector_type(8))) short short8;   // 8 x bf16 bits
typedef __attribute__((ext_vector_type(4))) float floatx4;
typedef __attribute__((ext_vector_type(4))) int   int4v;    // 16 B (i8 MFMA frag / i32 acc)

__device__ __forceinline__ short f2bf(float f) {
  union { float f; uint32_t u; } v; v.f = f;
  uint32_t r = v.u + 0x7fffu + ((v.u >> 16) & 1u);   // round-nearest-even
  return (short)(r >> 16);
}
__device__ __forceinline__ float bf2f(short s) {
  union { uint32_t u; float f; } v; v.u = ((uint32_t)(uint16_t)s) << 16;
  return v.f;
}
__device__ __forceinline__ int q8(float f, float inv) {
  int q = __float2int_rn(f * inv);
  return min(127, max(-127, q));
}

// async global->LDS, 16B per lane; LDS dest = wave-uniform base + lane*16
__device__ __forceinline__ void async16(const void* g, void* l) {
  __builtin_amdgcn_global_load_lds((const __attribute__((address_space(1))) void*)g,
                                   (__attribute__((address_space(3))) void*)l,
                                   16, 0, 0);
}

// ---------------------------------------------------------------------------
// prep: blocks [0,NTOK): LayerNorm rows -> int8 + per-row scale.
//       blocks [NTOK, NTOK+4096): weight transpose tiles -> Wt bf16.
// ---------------------------------------------------------------------------
__global__ __launch_bounds__(256) void prep_kernel(
    const float* __restrict__ x, const float* __restrict__ g,
    const float* __restrict__ b, char* __restrict__ xn_i8,
    float* __restrict__ xn_scl,
    const float* __restrict__ W0, const float* __restrict__ W1,
    const float* __restrict__ W2, const float* __restrict__ W3,
    short* __restrict__ Wt_base)
{
  const int bid = blockIdx.x;
  const int tid = threadIdx.x;

  if (bid < NTOK) {
    const int row = bid;
    const float4 v = ((const float4*)(x + (size_t)row * EDIM))[tid];
    float s  = v.x + v.y + v.z + v.w;
    float ss = v.x * v.x + v.y * v.y + v.z * v.z + v.w * v.w;
#pragma unroll
    for (int off = 32; off; off >>= 1) {
      s  += __shfl_xor(s, off);
      ss += __shfl_xor(ss, off);
    }
    __shared__ float ws_s[4], ws_ss[4], ws_m[4];
    const int lane = tid & 63, wave = tid >> 6;
    if (lane == 0) { ws_s[wave] = s; ws_ss[wave] = ss; }
    __syncthreads();
    s  = ws_s[0] + ws_s[1] + ws_s[2] + ws_s[3];
    ss = ws_ss[0] + ws_ss[1] + ws_ss[2] + ws_ss[3];

    const float mean = s * (1.0f / EDIM);
    const float var  = ss * (1.0f / EDIM) - mean * mean;
    const float rs   = rsqrtf(var + 1e-5f);

    const float4 gv = ((const float4*)g)[tid];
    const float4 bv = ((const float4*)b)[tid];
    const float n0 = (v.x - mean) * rs * gv.x + bv.x;
    const float n1 = (v.y - mean) * rs * gv.y + bv.y;
    const float n2 = (v.z - mean) * rs * gv.z + bv.z;
    const float n3 = (v.w - mean) * rs * gv.w + bv.w;

    float am = fmaxf(fmaxf(fabsf(n0), fabsf(n1)), fmaxf(fabsf(n2), fabsf(n3)));
#pragma unroll
    for (int off = 32; off; off >>= 1) am = fmaxf(am, __shfl_xor(am, off));
    if (lane == 0) ws_m[wave] = am;
    __syncthreads();
    am = fmaxf(fmaxf(ws_m[0], ws_m[1]), fmaxf(ws_m[2], ws_m[3]));

    const float inv = (am > 1e-30f) ? 127.0f / am : 0.0f;
    const int q0 = q8(n0, inv), q1 = q8(n1, inv), q2 = q8(n2, inv), q3 = q8(n3, inv);
    const uint32_t pack = (uint32_t)(q0 & 0xff) | ((uint32_t)(q1 & 0xff) << 8) |
                          ((uint32_t)(q2 & 0xff) << 16) | ((uint32_t)(q3 & 0xff) << 24);
    ((uint32_t*)(xn_i8 + (size_t)row * EDIM))[tid] = pack;
    if (tid == 0) xn_scl[row] = am * (1.0f / 127.0f);
  } else {
    const int t = bid - NTOK;
    const int z = t >> 10;
    const int rem = t & 1023;
    const int n0 = (rem & 31) * 32;
    const int k0 = (rem >> 5) * 32;
    const float* W = (z == 0) ? W0 : (z == 1) ? W1 : (z == 2) ? W2 : W3;
    short* Wt = Wt_base + (size_t)z * EDIM * EDIM;

    __shared__ float tile[32][33];
    const int tx = tid & 31;
    const int ty = tid >> 5;
#pragma unroll
    for (int i = 0; i < 4; ++i)
      tile[ty + i * 8][tx] = W[(size_t)(k0 + ty + i * 8) * EDIM + n0 + tx];
    __syncthreads();
#pragma unroll
    for (int i = 0; i < 4; ++i)
      Wt[(size_t)(n0 + ty + i * 8) * EDIM + k0 + tx] = f2bf(tile[tx][ty + i * 8]);
  }
}

// ---------------------------------------------------------------------------
// quant_w: one block per Wt row R (all 4 matrices): bf16 -> int8 + per-row
// (= per output column) scale.
// ---------------------------------------------------------------------------
__global__ __launch_bounds__(256) void quant_w(
    const short* __restrict__ Wt, char* __restrict__ w_i8,
    float* __restrict__ w_scl)
{
  const int R = blockIdx.x;      // 0..4095
  const int tid = threadIdx.x;
  const short4 s4 = ((const short4*)(Wt + (size_t)R * EDIM))[tid];
  const float w0 = bf2f(s4.x), w1 = bf2f(s4.y), w2 = bf2f(s4.z), w3 = bf2f(s4.w);

  float am = fmaxf(fmaxf(fabsf(w0), fabsf(w1)), fmaxf(fabsf(w2), fabsf(w3)));
#pragma unroll
  for (int off = 32; off; off >>= 1) am = fmaxf(am, __shfl_xor(am, off));
  __shared__ float wm[4];
  const int lane = tid & 63, wave = tid >> 6;
  if (lane == 0) wm[wave] = am;
  __syncthreads();
  am = fmaxf(fmaxf(wm[0], wm[1]), fmaxf(wm[2], wm[3]));

  const float inv = (am > 1e-30f) ? 127.0f / am : 0.0f;
  const int q0 = q8(w0, inv), q1 = q8(w1, inv), q2 = q8(w2, inv), q3 = q8(w3, inv);
  const uint32_t pack = (uint32_t)(q0 & 0xff) | ((uint32_t)(q1 & 0xff) << 8) |
                        ((uint32_t)(q2 & 0xff) << 16) | ((uint32_t)(q3 & 0xff) << 24);
  ((uint32_t*)(w_i8 + (size_t)R * EDIM))[tid] = pack;
  if (tid == 0) w_scl[R] = am * (1.0f / 127.0f);
}

// ---------------------------------------------------------------------------
// QKV projection, W8A8 int8 (R6-proven): 128x128 tile, K-tile = 64 i8,
// byte-identical LDS geometry to the m97 bf16 BK=32 tile. 16 k-iters.
// Epilogue dequant: bf16( acc * xn_scl[row] * w_scl[col] + bias ).
// 1D grid 768, XCD-aware decode (3 blocks/CU).
// ---------------------------------------------------------------------------
__global__ __launch_bounds__(256) void gemm_qkv_i8(
    const char* __restrict__ xn_i8, const float* __restrict__ xn_scl,
    const char* __restrict__ w_i8, const float* __restrict__ w_scl,
    const float* __restrict__ bq, const float* __restrict__ bk,
    const float* __restrict__ bv, short* __restrict__ qkv_base)
{
  __shared__ __align__(16) char As[128 * 64];   // 8 KB
  __shared__ __align__(16) char Bs[128 * 64];   // 8 KB

  const int bid  = blockIdx.x;           // 0..767
  const int xcd  = bid & 7;
  const int slot = bid >> 3;             // 0..95
  const int nz   = xcd * 3 + slot / 32;  // 0..23
  const int mt   = slot & 31;            // 0..31
  const int z    = nz >> 3;              // 0..2
  const int nt   = nz & 7;               // 0..7

  const char*  Bt   = w_i8 + (size_t)z * EDIM * EDIM;
  const float* bscl = w_scl + z * EDIM;
  const float* bias = (z == 0) ? bq : (z == 1) ? bk : bv;
  short* out        = qkv_base + (size_t)z * NTOK * EDIM;

  const int bm = mt * 128;
  const int bn = nt * 128;
  const int tid  = threadIdx.x;
  const int lane = tid & 63;
  const int wave = tid >> 6;

  int4v acc[4][4];
#pragma unroll
  for (int i = 0; i < 4; ++i)
#pragma unroll
    for (int j = 0; j < 4; ++j) { int4v zz = {0, 0, 0, 0}; acc[i][j] = zz; }

  const int lrow  = lane >> 2;          // 0..15
  const int lcolB = (lane & 3) * 16;    // byte col 0,16,32,48
  const char* gA0 = xn_i8 + (size_t)(bm + wave * 32 + lrow) * EDIM + lcolB;
  const char* gA1 = gA0 + (size_t)16 * EDIM;
  const char* gB0 = Bt + (size_t)(bn + wave * 32 + lrow) * EDIM + lcolB;
  const char* gB1 = gB0 + (size_t)16 * EDIM;
  char* lA0 = As + wave * 2048;
  char* lA1 = lA0 + 1024;
  char* lB0 = Bs + wave * 2048;
  char* lB1 = lB0 + 1024;

  const int wm  = (wave >> 1) * 64;
  const int wn  = (wave & 1) * 64;
  const int fr  = lane & 15;
  const int fqB = (lane >> 4) * 16;     // byte offset within 64-B row

  for (int k0 = 0; k0 < EDIM; k0 += 64) {
    async16(gA0, lA0); async16(gA1, lA1);
    async16(gB0, lB0); async16(gB1, lB1);
    gA0 += 64; gA1 += 64; gB0 += 64; gB1 += 64;
    __syncthreads();

    int4v af[4], bf[4];
#pragma unroll
    for (int mi = 0; mi < 4; ++mi)
      af[mi] = *(const int4v*)(As + (size_t)(wm + mi * 16 + fr) * 64 + fqB);
#pragma unroll
    for (int ni = 0; ni < 4; ++ni)
      bf[ni] = *(const int4v*)(Bs + (size_t)(wn + ni * 16 + fr) * 64 + fqB);
#pragma unroll
    for (int mi = 0; mi < 4; ++mi)
#pragma unroll
      for (int ni = 0; ni < 4; ++ni)
        acc[mi][ni] = __builtin_amdgcn_mfma_i32_16x16x64_i8(
            af[mi], bf[ni], acc[mi][ni], 0, 0, 0);
    __syncthreads();
  }

  const int r0 = bm + wm + ((lane >> 4) * 4);
  const int c0 = bn + wn + (lane & 15);
#pragma unroll
  for (int mi = 0; mi < 4; ++mi) {
    float sa[4];
#pragma unroll
    for (int r = 0; r < 4; ++r) sa[r] = xn_scl[r0 + mi * 16 + r];
#pragma unroll
    for (int ni = 0; ni < 4; ++ni) {
      const int4v v = acc[mi][ni];
      const int col = c0 + ni * 16;
      const float sb = bscl[col];
      const float bb = bias[col];
#pragma unroll
      for (int r = 0; r < 4; ++r) {
        const int row = r0 + mi * 16 + r;
        out[(size_t)row * EDIM + col] = f2bf((float)v[r] * (sa[r] * sb) + bb);
      }
    }
  }
}

// ---------------------------------------------------------------------------
// O projection, W8A8 int8 with per-(row,head) A-scales. K-chunk 64 = one head,
// so dequant is per-chunk: facc += sa[row][head] * cvt(i8-MFMA chunk result).
// sb[col] + bias + residual in epilogue. 64x128 tile, 512 blocks, 16 k-iters.
// ---------------------------------------------------------------------------
__global__ __launch_bounds__(256) void gemm_o_i8(
    const char* __restrict__ A8, const float* __restrict__ a_scl,
    const char* __restrict__ w_i8, const float* __restrict__ w_scl,
    const float* __restrict__ bo, const float* __restrict__ residual,
    float* __restrict__ out)
{
  __shared__ __align__(16) char As[64 * 64];     // 4 KB
  __shared__ __align__(16) char Bs[128 * 64];    // 8 KB
  __shared__ float sa_lds[64 * 17];              // per-(row,head) scales, padded

  const int bm = blockIdx.x * 64;
  const int bn = blockIdx.y * 128;
  const int tid  = threadIdx.x;
  const int lane = tid & 63;
  const int wave = tid >> 6;

#pragma unroll
  for (int i = 0; i < 4; ++i) {
    const int e = tid + i * 256;          // 0..1023
    const int row = e >> 4, h = e & 15;
    sa_lds[row * 17 + h] = a_scl[(size_t)(bm + row) * NHEAD + h];
  }

  floatx4 facc[2][4];
#pragma unroll
  for (int i = 0; i < 2; ++i)
#pragma unroll
    for (int j = 0; j < 4; ++j) { floatx4 zz = {0.f, 0.f, 0.f, 0.f}; facc[i][j] = zz; }

  const int lrow  = lane >> 2;
  const int lcolB = (lane & 3) * 16;
  const char* gA0 = A8 + (size_t)(bm + wave * 16 + lrow) * EDIM + lcolB;
  const char* gB0 = w_i8 + (size_t)3 * EDIM * EDIM +
                    (size_t)(bn + wave * 32 + lrow) * EDIM + lcolB;
  const char* gB1 = gB0 + (size_t)16 * EDIM;
  char* lA0 = As + wave * 1024;
  char* lB0 = Bs + wave * 2048;
  char* lB1 = lB0 + 1024;

  const int wm  = (wave >> 1) * 32;   // 0 or 32
  const int wn  = (wave & 1) * 64;    // 0 or 64
  const int fr  = lane & 15;
  const int fqB = (lane >> 4) * 16;
  const int q4  = lane >> 4;

  for (int ki = 0; ki < 16; ++ki) {
    async16(gA0, lA0);
    async16(gB0, lB0); async16(gB1, lB1);
    gA0 += 64; gB0 += 64; gB1 += 64;
    __syncthreads();

    int4v af[2], bf[4];
#pragma unroll
    for (int mi = 0; mi < 2; ++mi)
      af[mi] = *(const int4v*)(As + (size_t)(wm + mi * 16 + fr) * 64 + fqB);
#pragma unroll
    for (int ni = 0; ni < 4; ++ni)
      bf[ni] = *(const int4v*)(Bs + (size_t)(wn + ni * 16 + fr) * 64 + fqB);

    float sa_v[2][4];
#pragma unroll
    for (int mi = 0; mi < 2; ++mi)
#pragma unroll
      for (int r = 0; r < 4; ++r)
        sa_v[mi][r] = sa_lds[(wm + mi * 16 + q4 * 4 + r) * 17 + ki];

#pragma unroll
    for (int mi = 0; mi < 2; ++mi)
#pragma unroll
      for (int ni = 0; ni < 4; ++ni) {
        const int4v zz = {0, 0, 0, 0};
        const int4v t = __builtin_amdgcn_mfma_i32_16x16x64_i8(
            af[mi], bf[ni], zz, 0, 0, 0);
#pragma unroll
        for (int r = 0; r < 4; ++r)
          facc[mi][ni][r] += sa_v[mi][r] * (float)t[r];
      }
    __syncthreads();
  }

  const int r0 = bm + wm + q4 * 4;
  const int c0 = bn + wn + (lane & 15);
#pragma unroll
  for (int mi = 0; mi < 2; ++mi)
#pragma unroll
    for (int ni = 0; ni < 4; ++ni) {
      const int col = c0 + ni * 16;
      const float sb = w_scl[3 * EDIM + col];
      const float bb = bo[col];
#pragma unroll
      for (int r = 0; r < 4; ++r) {
        const int row = r0 + mi * 16 + r;
        const size_t idx = (size_t)row * EDIM + col;
        out[idx] = residual[idx] + facc[mi][ni][r] * sb + bb;
      }
    }
}

// ---------------------------------------------------------------------------
// MFMA attention (bf16 Q/K/V); epilogue quantizes output to i8 with
// per-(row,head) scale for the i8 O-projection.
// ---------------------------------------------------------------------------
#define VT_LD 80
#define PB_LD 40

__global__ __launch_bounds__(256) void attn_mfma(
    const short* __restrict__ Q, const short* __restrict__ K,
    const short* __restrict__ V, char* __restrict__ O8,
    float* __restrict__ a_scl)
{
  const int tid  = threadIdx.x;
  const int lane = tid & 63;
  const int wave = tid >> 6;
  const int quad = lane >> 4;
  const int l16  = lane & 15;

  const int bh = blockIdx.y;
  const int h  = bh & (NHEAD - 1);
  const int b  = bh >> 4;
  const int s_blk = blockIdx.x * 64;
  const int col0  = h * DHEAD;

  __shared__ __align__(16) short VT[64 * VT_LD];
  __shared__ __align__(16) short Pb[4][16 * PB_LD];

  for (int task = tid; task < 320; task += 256) {
    const int kp  = task >> 3;
    const int dg  = task & 7;
    const int kk0 = kp * 2;
    int sA = s_blk - 15 + kk0;
    int sB = sA + 1;
    if (sA < 0) sA += SLEN;  if (sA >= SLEN) sA -= SLEN;
    if (sB < 0) sB += SLEN;  if (sB >= SLEN) sB -= SLEN;
    const short8 vA = *(const short8*)(V + (size_t)(sA * BSZ + b) * EDIM + col0 + dg * 8);
    const short8 vB = *(const short8*)(V + (size_t)(sB * BSZ + b) * EDIM + col0 + dg * 8);
#pragma unroll
    for (int j = 0; j < 8; ++j) {
      const int d = dg * 8 + j;
      const uint32_t pack = (uint32_t)(uint16_t)vA[j] | ((uint32_t)(uint16_t)vB[j] << 16);
      *(uint32_t*)&VT[d * VT_LD + kk0] = pack;
    }
  }

  const int sw = s_blk + wave * 16;
  short8 aq[2];
  {
    const size_t base = (size_t)((sw + l16) * BSZ + b) * EDIM + col0 + quad * 8;
    aq[0] = *(const short8*)(Q + base);
    aq[1] = *(const short8*)(Q + base + 32);
  }
  short8 bkf[2][2];
#pragma unroll
  for (int T = 0; T < 2; ++T) {
    int ks = sw - 15 + T * 16 + l16;
    if (ks < 0) ks += SLEN;
    if (ks >= SLEN) ks -= SLEN;
    const size_t base = (size_t)(ks * BSZ + b) * EDIM + col0 + quad * 8;
    bkf[T][0] = *(const short8*)(K + base);
    bkf[T][1] = *(const short8*)(K + base + 32);
  }

  floatx4 S[2];
  { floatx4 zz = {0.f, 0.f, 0.f, 0.f}; S[0] = zz; S[1] = zz; }
#pragma unroll
  for (int T = 0; T < 2; ++T) {
    S[T] = __builtin_amdgcn_mfma_f32_16x16x32_bf16(aq[0], bkf[T][0], S[T], 0, 0, 0);
    S[T] = __builtin_amdgcn_mfma_f32_16x16x32_bf16(aq[1], bkf[T][1], S[T], 0, 0, 0);
  }

  float sc[2][4];
#pragma unroll
  for (int T = 0; T < 2; ++T)
#pragma unroll
    for (int r = 0; r < 4; ++r) {
      const int m = quad * 4 + r;
      const int c = T * 16 + l16;
      const int d = c - m;
      sc[T][r] = (d >= 0 && d <= 15) ? S[T][r] * 0.125f : -1e30f;
    }
  float mx[4], sm[4];
#pragma unroll
  for (int r = 0; r < 4; ++r) mx[r] = fmaxf(sc[0][r], sc[1][r]);
#pragma unroll
  for (int off = 1; off <= 8; off <<= 1)
#pragma unroll
    for (int r = 0; r < 4; ++r) mx[r] = fmaxf(mx[r], __shfl_xor(mx[r], off));
  float p[2][4];
#pragma unroll
  for (int r = 0; r < 4; ++r) {
    p[0][r] = __expf(sc[0][r] - mx[r]);
    p[1][r] = __expf(sc[1][r] - mx[r]);
    sm[r] = p[0][r] + p[1][r];
  }
#pragma unroll
  for (int off = 1; off <= 8; off <<= 1)
#pragma unroll
    for (int r = 0; r < 4; ++r) sm[r] += __shfl_xor(sm[r], off);

  __syncthreads();

  short* Pw = Pb[wave];
#pragma unroll
  for (int T = 0; T < 2; ++T)
#pragma unroll
    for (int r = 0; r < 4; ++r) {
      const int m = quad * 4 + r;
      const int c = T * 16 + l16;
      Pw[m * PB_LD + c] = f2bf(p[T][r]);
    }
  __syncthreads();
  const short8 ap = *(const short8*)(Pw + l16 * PB_LD + quad * 8);

  floatx4 Oacc[4];
  { floatx4 zz = {0.f, 0.f, 0.f, 0.f}; Oacc[0] = zz; Oacc[1] = zz; Oacc[2] = zz; Oacc[3] = zz; }
#pragma unroll
  for (int nt = 0; nt < 4; ++nt) {
    const short8 bv = *(const short8*)(VT + (nt * 16 + l16) * VT_LD + wave * 16 + quad * 8);
    Oacc[nt] = __builtin_amdgcn_mfma_f32_16x16x32_bf16(ap, bv, Oacc[nt], 0, 0, 0);
  }

  // ---- i8 quantization of output rows (per row, this head)
  float vv[4][4];   // [nt][r]
  float am[4] = {0.f, 0.f, 0.f, 0.f};
#pragma unroll
  for (int nt = 0; nt < 4; ++nt)
#pragma unroll
    for (int r = 0; r < 4; ++r) {
      const float v = Oacc[nt][r] / sm[r];
      vv[nt][r] = v;
      am[r] = fmaxf(am[r], fabsf(v));
    }
#pragma unroll
  for (int off = 1; off <= 8; off <<= 1)
#pragma unroll
    for (int r = 0; r < 4; ++r) am[r] = fmaxf(am[r], __shfl_xor(am[r], off));

  float inv[4];
#pragma unroll
  for (int r = 0; r < 4; ++r) inv[r] = (am[r] > 1e-30f) ? 127.0f / am[r] : 0.0f;

#pragma unroll
  for (int nt = 0; nt < 4; ++nt)
#pragma unroll
    for (int r = 0; r < 4; ++r) {
      const int m = quad * 4 + r;
      const int row = (sw + m) * BSZ + b;
      O8[(size_t)row * EDIM + col0 + nt * 16 + l16] = (char)q8(vv[nt][r], inv[r]);
    }
  if (l16 == 0) {
#pragma unroll
    for (int r = 0; r < 4; ++r) {
      const int m = quad * 4 + r;
      const int row = (sw + m) * BSZ + b;
      a_scl[(size_t)row * NHEAD + h] = am[r] * (1.0f / 127.0f);
    }
  }
}

// ---------------------------------------------------------------------------
extern "C" void kernel_launch(void* const* d_in, const int* in_sizes, int n_in,
                              void* d_out, int out_size, void* d_ws, size_t ws_size,
                              hipStream_t stream) {
  const float* x    = (const float*)d_in[0];
  const float* ln_g = (const float*)d_in[1];
  const float* ln_b = (const float*)d_in[2];
  const float* Wq   = (const float*)d_in[3];
  const float* bq   = (const float*)d_in[4];
  const float* Wk   = (const float*)d_in[5];
  const float* bk   = (const float*)d_in[6];
  const float* Wv   = (const float*)d_in[7];
  const float* bv   = (const float*)d_in[8];
  const float* Wo   = (const float*)d_in[9];
  const float* bo   = (const float*)d_in[10];
  float* out = (float*)d_out;

  char* ws = (char*)d_ws;
  char*  xn_i8   = ws;                                      // 4 MB
  short* Wt      = (short*)(ws + ((size_t)4  << 20));       // 8 MB: 4x Wt bf16
  char*  w_i8    = ws + ((size_t)12 << 20);                 // 4 MB: 4x Wt i8
  short* QKV     = (short*)(ws + ((size_t)16 << 20));       // 24 MB bf16
  char*  attn_i8 = ws + ((size_t)40 << 20);                 // 4 MB i8
  float* xn_scl  = (float*)(ws + ((size_t)44 << 20));       // 16 KB
  float* w_scl   = (float*)(ws + ((size_t)44 << 20) + (1 << 16)); // 16 KB
  float* a_scl   = (float*)(ws + ((size_t)44 << 20) + (2 << 16)); // 256 KB

  prep_kernel<<<NTOK + 4096, 256, 0, stream>>>(x, ln_g, ln_b, xn_i8, xn_scl,
                                               Wq, Wk, Wv, Wo, Wt);
  quant_w<<<4 * EDIM, 256, 0, stream>>>(Wt, w_i8, w_scl);
  gemm_qkv_i8<<<768, 256, 0, stream>>>(xn_i8, xn_scl, w_i8, w_scl,
                                       bq, bk, bv, QKV);
  attn_mfma<<<dim3(SLEN / 64, BSZ * NHEAD), 256, 0, stream>>>(
      QKV, QKV + (size_t)NTOK * EDIM, QKV + (size_t)2 * NTOK * EDIM,
      attn_i8, a_scl);
  gemm_o_i8<<<dim3(NTOK / 64, EDIM / 128), 256, 0, stream>>>(
      attn_i8, a_scl, w_i8, w_scl, bo, x, out);
}